// Round 4
// baseline (700.276 us; speedup 1.0000x reference)
//
#include <hip/hip_runtime.h>
#include <hip/hip_bf16.h>

using bf16x8 = __attribute__((ext_vector_type(8))) short;
using f32x4  = __attribute__((ext_vector_type(4))) float;

#define MFMA_BF16(a, b, c) __builtin_amdgcn_mfma_f32_16x16x32_bf16((a), (b), (c), 0, 0, 0)

__device__ __forceinline__ unsigned short f2bf(float x) {
  union { float f; unsigned int u; } v; v.f = x;
  unsigned int r = v.u + 0x7fffu + ((v.u >> 16) & 1u);
  return (unsigned short)(r >> 16);
}

__device__ __forceinline__ void gload16(const void* g, void* l) {
  __builtin_amdgcn_global_load_lds(
      (const __attribute__((address_space(1))) unsigned int*)g,
      (__attribute__((address_space(3))) unsigned int*)l, 16, 0, 0);
}

// ---------------- f32 -> bf16 convert ----------------
__global__ __launch_bounds__(256) void cvt_f32_bf16(const float* __restrict__ in,
                                                    unsigned short* __restrict__ out, int n) {
  int i = (blockIdx.x * 256 + threadIdx.x) * 4;
  if (i >= n) return;
  float4 f = *(const float4*)(in + i);
  ushort4 o;
  o.x = f2bf(f.x); o.y = f2bf(f.y); o.z = f2bf(f.z); o.w = f2bf(f.w);
  *(ushort4*)(out + i) = o;
}

// ---------------- BT-GEMM: C[m][n] = sum_k A[m][k] * Bw[n][k] ----------------
// M=8192, K=1024 baked. 128x128 tile, BK=32, 4 waves each 64x64.
// MODE 3: fused QKV (Bw = [3072][1024] qw|kw|vw). RoPE on Q,K -> [BH,S,DK];
//         V transposed -> [BH,DK,S]. Epilogue goes through an LDS transpose so
//         every global store is 1 KB contiguous per wave instruction (fixes the
//         64x HBM write amplification seen with scattered 2-byte stores).
// MODE 2: f32 out, [M,1024] (final projection; stores already line-coalesced)
template <int MODE>
__global__ __launch_bounds__(256) void gemm_bt(const unsigned short* __restrict__ A,
                                               const unsigned short* __restrict__ Bw,
                                               void* __restrict__ outp,
                                               const int* __restrict__ pos) {
  constexpr int K = 1024;
  constexpr int SMEM_ELEMS = (MODE == 3) ? 128 * 136 : 128 * 64;
  __shared__ __align__(16) unsigned short smem[SMEM_ELEMS];  // staging; MODE3: reused as C-tile
  const int tid  = threadIdx.x;
  const int lane = tid & 63, wave = tid >> 6;
  const int wr = wave >> 1, wc = wave & 1;
  // XCD-aware remap: XCD x owns by in [8x, 8x+8) -> A panel fetched once per XCD
  const int bid = blockIdx.x + blockIdx.y * gridDim.x;
  const int xcd = bid & 7, loc = bid >> 3;
  const int bn = loc % gridDim.x;
  const int by = xcd * 8 + loc / gridDim.x;
  const int bm0 = by * 128, bn0 = bn * 128;
  const int lrow = lane & 15, lko = (lane >> 4) * 8;
  const int hi = lane >> 4;
  const int srow = wave * 16 + (lane >> 2);
  const int scol = (lane & 3) * 8;
  const unsigned short* gA = A + (size_t)(bm0 + srow) * K + scol;
  const unsigned short* gB = Bw + (size_t)(bn0 + srow) * K + scol;
  char* lA = (char*)smem + wave * 1024;          // As: first 8 KB
  char* lB = (char*)smem + 8192 + wave * 1024;   // Bs: next 8 KB
  const f32x4 z = {0.f, 0.f, 0.f, 0.f};
  f32x4 acc[4][4];
#pragma unroll
  for (int i = 0; i < 4; ++i)
#pragma unroll
    for (int j = 0; j < 4; ++j) acc[i][j] = z;

  for (int k0 = 0; k0 < K; k0 += 32) {
    __syncthreads();
    gload16(gA + k0, lA);
    gload16(gA + k0 + (size_t)64 * K, lA + 4096);
    gload16(gB + k0, lB);
    gload16(gB + k0 + (size_t)64 * K, lB + 4096);
    __syncthreads();
    bf16x8 af[4], bfr[4];
#pragma unroll
    for (int mi = 0; mi < 4; ++mi)
      af[mi] = *(const bf16x8*)&smem[(wr * 64 + mi * 16 + lrow) * 32 + lko];
#pragma unroll
    for (int ni = 0; ni < 4; ++ni)
      bfr[ni] = *(const bf16x8*)&smem[4096 + (wc * 64 + ni * 16 + lrow) * 32 + lko];
#pragma unroll
    for (int mi = 0; mi < 4; ++mi)
#pragma unroll
      for (int ni = 0; ni < 4; ++ni)
        acc[mi][ni] = MFMA_BF16(af[mi], bfr[ni], acc[mi][ni]);
  }

  if (MODE == 2) {
#pragma unroll
    for (int mi = 0; mi < 4; ++mi)
#pragma unroll
      for (int r = 0; r < 4; ++r) {
        const int row = bm0 + wr * 64 + mi * 16 + hi * 4 + r;
#pragma unroll
        for (int ni = 0; ni < 4; ++ni) {
          const int col = bn0 + wc * 64 + ni * 16 + lrow;
          ((float*)outp)[(size_t)row * 1024 + col] = acc[mi][ni][r];
        }
      }
    return;
  }

  // ---- MODE 3 epilogue via LDS transpose ----
  const int proj = bn0 >> 10;          // 0=Q 1=K 2=V, block-uniform (tile never crosses)
  const int h0 = (bn0 & 1023) >> 6;    // first of 2 heads in this tile
  const int bb = bm0 >> 11, s0 = bm0 & 2047;
  unsigned short* Qr  = (unsigned short*)outp;
  unsigned short* Kr  = Qr + (size_t)8388608;
  unsigned short* Vtr = Qr + (size_t)16777216;
  __syncthreads();  // all waves done reading As/Bs
  if (proj < 2) {
    // RoPE in registers (pair partner in lane^1), then Cs[s_local][c_local]
#pragma unroll
    for (int mi = 0; mi < 4; ++mi)
#pragma unroll
      for (int ni = 0; ni < 4; ++ni) {
        const int col = wc * 64 + ni * 16 + lrow;
        const int d = col & 63;
        const float invf = exp2f((float)(d & ~1) * (-13.287712379549609f / 64.0f));
#pragma unroll
        for (int r = 0; r < 4; ++r) {
          const int row = wr * 64 + mi * 16 + hi * 4 + r;
          const float p = (float)pos[bm0 + row];
          float sn, cs;
          sincosf(p * invf, &sn, &cs);
          const float v = acc[mi][ni][r];
          const float other = __shfl_xor(v, 1);
          const float rv = (d & 1) ? (other * sn + v * cs) : (v * cs - other * sn);
          smem[row * 136 + col] = f2bf(rv);
        }
      }
    __syncthreads();
    unsigned short* dst = proj ? Kr : Qr;
#pragma unroll
    for (int it = 0; it < 8; ++it) {
      const int idx = wave * 8 + it;
      const int hl = idx >> 4, sg = idx & 15;
      const int sl = sg * 8 + (lane >> 3);
      const int ch = (lane & 7) * 8;
      const bf16x8 val = *(const bf16x8*)&smem[sl * 136 + hl * 64 + ch];
      *(bf16x8*)&dst[((size_t)(bb * 16 + h0 + hl) * 2048 + s0 + sl) * 64 + ch] = val;
    }
  } else {
    // V: CsT[c_local][s_local] (transpose at LDS-write, packed r quad = b64)
#pragma unroll
    for (int mi = 0; mi < 4; ++mi)
#pragma unroll
      for (int ni = 0; ni < 4; ++ni) {
        const int col = wc * 64 + ni * 16 + lrow;
        ushort4 pk;
        pk.x = f2bf(acc[mi][ni][0]); pk.y = f2bf(acc[mi][ni][1]);
        pk.z = f2bf(acc[mi][ni][2]); pk.w = f2bf(acc[mi][ni][3]);
        *(ushort4*)&smem[col * 136 + wr * 64 + mi * 16 + hi * 4] = pk;
      }
    __syncthreads();
#pragma unroll
    for (int it = 0; it < 8; ++it) {
      const int idx = wave * 8 + it;
      const int cl = idx * 4 + (lane >> 4);
      const int sc = (lane & 15) * 8;
      const bf16x8 val = *(const bf16x8*)&smem[cl * 136 + sc];
      *(bf16x8*)&Vtr[((size_t)(bb * 16 + h0 + (cl >> 6)) * 64 + (cl & 63)) * 2048 + s0 + sc] = val;
    }
  }
}

// ---------------- causal flash attention (swapped QK^T, LDS-staged K/V) ----------------
__global__ __launch_bounds__(256) void attn_fwd(const unsigned short* __restrict__ Q,
                                                const unsigned short* __restrict__ Kk,
                                                const unsigned short* __restrict__ Vt,
                                                unsigned short* __restrict__ O) {
  __shared__ __align__(16) unsigned short Ks[4096];   // [64][64] swizzled
  __shared__ __align__(16) unsigned short Vs[4096];   // [64 d][64 kv] swizzled
  __shared__ __align__(16) unsigned short Plds[4][16][72];
  const int p = blockIdx.x;
  const int L = (p & 7) * 128 + (p >> 3);  // XCD swizzle: 8 heads/XCD
  const int bh = L >> 4, pair = L & 15;
  const int tid = threadIdx.x;
  const int lane = tid & 63, wave = tid >> 6;
  const int lrow = lane & 15, hi = lane >> 4;
  const unsigned short* Qb = Q + (size_t)bh * 2048 * 64;
  const unsigned short* Kb = Kk + (size_t)bh * 2048 * 64;
  const unsigned short* Vb = Vt + (size_t)bh * 64 * 2048;
  const int rowA = tid >> 3;
  const int colA = ((tid & 7) ^ (rowA & 7)) * 8;
  const int rowB = rowA + 32;
  const int colB = ((tid & 7) ^ (rowB & 7)) * 8;
  char* kBase0 = (char*)Ks + wave * 1024;
  char* kBase1 = (char*)Ks + 4096 + wave * 1024;
  char* vBase0 = (char*)Vs + wave * 1024;
  char* vBase1 = (char*)Vs + 4096 + wave * 1024;
  const int b = bh >> 4, h = bh & 15;
  const f32x4 z = {0.f, 0.f, 0.f, 0.f};
  constexpr float SCALE = 0.18033688011112042f;  // 0.125 * log2(e)

  for (int half = 0; half < 2; ++half) {
    const int qb = half ? (31 - pair) : pair;
    const int qrow = qb * 64 + wave * 16;
    const int qg = qrow + lrow;
    const bf16x8 qf0 = *(const bf16x8*)(Qb + (size_t)qg * 64 + hi * 8);
    const bf16x8 qf1 = *(const bf16x8*)(Qb + (size_t)qg * 64 + 32 + hi * 8);
    f32x4 acc[4] = {z, z, z, z};
    float m = -1e30f, l = 0.f;

    for (int t = 0; t <= qb; ++t) {
      const int kv0 = t * 64;
      __syncthreads();
      gload16(Kb + (size_t)(kv0 + rowA) * 64 + colA, kBase0);
      gload16(Kb + (size_t)(kv0 + rowB) * 64 + colB, kBase1);
      gload16(Vb + (size_t)rowA * 2048 + kv0 + colA, vBase0);
      gload16(Vb + (size_t)rowB * 2048 + kv0 + colB, vBase1);
      __syncthreads();

      f32x4 st[4];
#pragma unroll
      for (int n = 0; n < 4; ++n) {
        const int rk = n * 16 + lrow;
        const int sw = lrow & 7;
        const bf16x8 kf0 = *(const bf16x8*)((char*)Ks + rk * 128 + ((hi ^ sw) * 16));
        const bf16x8 kf1 = *(const bf16x8*)((char*)Ks + rk * 128 + (((4 + hi) ^ sw) * 16));
        st[n] = MFMA_BF16(kf0, qf0, z);
        st[n] = MFMA_BF16(kf1, qf1, st[n]);
      }
      float pv[16];
      float pmax = -1e30f;
      const bool diag = (t == qb);
#pragma unroll
      for (int n = 0; n < 4; ++n)
#pragma unroll
        for (int r = 0; r < 4; ++r) {
          float v = st[n][r] * SCALE;
          if (diag && (kv0 + n * 16 + hi * 4 + r > qg)) v = -1e30f;
          pv[n * 4 + r] = v;
          pmax = fmaxf(pmax, v);
        }
      pmax = fmaxf(pmax, __shfl_xor(pmax, 16));
      pmax = fmaxf(pmax, __shfl_xor(pmax, 32));
      const float newm = fmaxf(m, pmax);
      const float scl = exp2f(m - newm);
      float rs = 0.f;
#pragma unroll
      for (int i = 0; i < 16; ++i) {
        pv[i] = exp2f(pv[i] - newm);
        rs += pv[i];
      }
      rs += __shfl_xor(rs, 16);
      rs += __shfl_xor(rs, 32);
      l = l * scl + rs;
      m = newm;
#pragma unroll
      for (int dt = 0; dt < 4; ++dt) acc[dt] *= scl;
#pragma unroll
      for (int n = 0; n < 4; ++n) {
        ushort4 pk;
        pk.x = f2bf(pv[n * 4 + 0]); pk.y = f2bf(pv[n * 4 + 1]);
        pk.z = f2bf(pv[n * 4 + 2]); pk.w = f2bf(pv[n * 4 + 3]);
        *(ushort4*)&Plds[wave][lrow][n * 16 + hi * 4] = pk;
      }
      const bf16x8 pf0 = *(const bf16x8*)&Plds[wave][lrow][hi * 8];
      const bf16x8 pf1 = *(const bf16x8*)&Plds[wave][lrow][32 + hi * 8];
#pragma unroll
      for (int dt = 0; dt < 4; ++dt) {
        const int rv = dt * 16 + lrow;
        const int sw = lrow & 7;
        const bf16x8 vf0 = *(const bf16x8*)((char*)Vs + rv * 128 + ((hi ^ sw) * 16));
        const bf16x8 vf1 = *(const bf16x8*)((char*)Vs + rv * 128 + (((4 + hi) ^ sw) * 16));
        acc[dt] = MFMA_BF16(vf0, pf0, acc[dt]);
        acc[dt] = MFMA_BF16(vf1, pf1, acc[dt]);
      }
    }

    const float inv = 1.0f / l;
#pragma unroll
    for (int dt = 0; dt < 4; ++dt) {
      ushort4 ov;
      ov.x = f2bf(acc[dt][0] * inv); ov.y = f2bf(acc[dt][1] * inv);
      ov.z = f2bf(acc[dt][2] * inv); ov.w = f2bf(acc[dt][3] * inv);
      *(ushort4*)&O[((size_t)b * 2048 + qg) * 1024 + h * 64 + dt * 16 + hi * 4] = ov;
    }
  }
}

extern "C" void kernel_launch(void* const* d_in, const int* in_sizes, int n_in,
                              void* d_out, int out_size, void* d_ws, size_t ws_size,
                              hipStream_t stream) {
  const float* x  = (const float*)d_in[0];
  const float* qw = (const float*)d_in[1];
  const float* kw = (const float*)d_in[2];
  const float* vw = (const float*)d_in[3];
  const float* ow = (const float*)d_in[4];
  const int* pos  = (const int*)d_in[5];
  float* out = (float*)d_out;

  unsigned short* xb  = (unsigned short*)d_ws;            // [8192,1024]
  unsigned short* qwb = xb  + (size_t)8192 * 1024;        // [3072,1024] fused qkv
  unsigned short* kwb = qwb + (size_t)1024 * 1024;
  unsigned short* vwb = kwb + (size_t)1024 * 1024;
  unsigned short* owb = vwb + (size_t)1024 * 1024;
  unsigned short* Qr  = owb + (size_t)1024 * 1024;        // [BH,S,DK]
  unsigned short* Kr  = Qr  + (size_t)8192 * 1024;        // [BH,S,DK]
  unsigned short* Vtr = Kr  + (size_t)8192 * 1024;        // [BH,DK,S]
  unsigned short* AO  = Vtr + (size_t)8192 * 1024;        // [8192,1024]

  cvt_f32_bf16<<<8192, 256, 0, stream>>>(x,  xb,  8192 * 1024);
  cvt_f32_bf16<<<1024, 256, 0, stream>>>(qw, qwb, 1024 * 1024);
  cvt_f32_bf16<<<1024, 256, 0, stream>>>(kw, kwb, 1024 * 1024);
  cvt_f32_bf16<<<1024, 256, 0, stream>>>(vw, vwb, 1024 * 1024);
  cvt_f32_bf16<<<1024, 256, 0, stream>>>(ow, owb, 1024 * 1024);

  dim3 gqkv(24, 64);  // (3072/128, 8192/128)
  gemm_bt<3><<<gqkv, 256, 0, stream>>>(xb, qwb, Qr, pos);
  attn_fwd<<<1024, 256, 0, stream>>>(Qr, Kr, Vtr, AO);
  dim3 go(8, 64);
  gemm_bt<2><<<go, 256, 0, stream>>>(AO, owb, out, nullptr);
}

// Round 5
// 556.896 us; speedup vs baseline: 1.2575x; 1.2575x over previous
//
#include <hip/hip_runtime.h>
#include <hip/hip_bf16.h>

using bf16x8 = __attribute__((ext_vector_type(8))) short;
using f32x4  = __attribute__((ext_vector_type(4))) float;

#define MFMA_BF16(a, b, c) __builtin_amdgcn_mfma_f32_16x16x32_bf16((a), (b), (c), 0, 0, 0)

__device__ __forceinline__ unsigned short f2bf(float x) {
  union { float f; unsigned int u; } v; v.f = x;
  unsigned int r = v.u + 0x7fffu + ((v.u >> 16) & 1u);
  return (unsigned short)(r >> 16);
}

__device__ __forceinline__ void gload16(const void* g, void* l) {
  __builtin_amdgcn_global_load_lds(
      (const __attribute__((address_space(1))) unsigned int*)g,
      (__attribute__((address_space(3))) unsigned int*)l, 16, 0, 0);
}

// ---------------- f32 -> bf16 convert ----------------
__global__ __launch_bounds__(256) void cvt_f32_bf16(const float* __restrict__ in,
                                                    unsigned short* __restrict__ out, int n) {
  int i = (blockIdx.x * 256 + threadIdx.x) * 4;
  if (i >= n) return;
  float4 f = *(const float4*)(in + i);
  ushort4 o;
  o.x = f2bf(f.x); o.y = f2bf(f.y); o.z = f2bf(f.z); o.w = f2bf(f.w);
  *(ushort4*)(out + i) = o;
}

// ---------------- BT-GEMM: C[m][n] = sum_k A[m][k] * Bw[n][k] ----------------
// M=8192, N=K=1024 baked. 128x128 tile, BK=32, 4 waves each 64x64. One proj per
// launch (fused variant caused a 3 GB/dispatch HBM write stream - register
// pressure suspect). Epilogues route through LDS so every global store is 1 KB
// contiguous per wave instruction.
// MODE 0: RoPE epilogue, bf16 out [BH,S,DK] (Q or K)
// MODE 1: bf16 out transposed [BH,DK,S]     (V)
// MODE 2: f32 out [M,1024]                  (final projection)
template <int MODE>
__global__ __launch_bounds__(256, 2) void gemm_bt(const unsigned short* __restrict__ A,
                                                  const unsigned short* __restrict__ Bw,
                                                  void* __restrict__ outp,
                                                  const int* __restrict__ pos) {
  constexpr int K = 1024;
  constexpr int SMEM_ELEMS = (MODE == 2) ? 128 * 64 : 128 * 136;
  __shared__ __align__(16) unsigned short smem[SMEM_ELEMS];  // 16KB staging; MODE<2: reused as C-tile
  const int tid  = threadIdx.x;
  const int lane = tid & 63, wave = tid >> 6;
  const int wr = wave >> 1, wc = wave & 1;
  const int bm0 = blockIdx.y * 128, bn0 = blockIdx.x * 128;
  const int lrow = lane & 15, lko = (lane >> 4) * 8;
  const int hi = lane >> 4;
  const int srow = wave * 16 + (lane >> 2);
  const int scol = (lane & 3) * 8;
  const unsigned short* gA = A + (size_t)(bm0 + srow) * K + scol;
  const unsigned short* gB = Bw + (size_t)(bn0 + srow) * K + scol;
  char* lA = (char*)smem + wave * 1024;          // As: [0, 8KB)
  char* lB = (char*)smem + 8192 + wave * 1024;   // Bs: [8KB, 16KB)
  const f32x4 z = {0.f, 0.f, 0.f, 0.f};
  f32x4 acc[4][4];
#pragma unroll
  for (int i = 0; i < 4; ++i)
#pragma unroll
    for (int j = 0; j < 4; ++j) acc[i][j] = z;

  for (int k0 = 0; k0 < K; k0 += 32) {
    __syncthreads();
    gload16(gA + k0, lA);
    gload16(gA + k0 + (size_t)64 * K, lA + 4096);
    gload16(gB + k0, lB);
    gload16(gB + k0 + (size_t)64 * K, lB + 4096);
    __syncthreads();
    bf16x8 af[4], bfr[4];
#pragma unroll
    for (int mi = 0; mi < 4; ++mi)
      af[mi] = *(const bf16x8*)&smem[(wr * 64 + mi * 16 + lrow) * 32 + lko];
#pragma unroll
    for (int ni = 0; ni < 4; ++ni)
      bfr[ni] = *(const bf16x8*)&smem[4096 + (wc * 64 + ni * 16 + lrow) * 32 + lko];
#pragma unroll
    for (int mi = 0; mi < 4; ++mi)
#pragma unroll
      for (int ni = 0; ni < 4; ++ni)
        acc[mi][ni] = MFMA_BF16(af[mi], bfr[ni], acc[mi][ni]);
  }

  if (MODE == 2) {
#pragma unroll
    for (int mi = 0; mi < 4; ++mi)
#pragma unroll
      for (int r = 0; r < 4; ++r) {
        const int row = bm0 + wr * 64 + mi * 16 + hi * 4 + r;
#pragma unroll
        for (int ni = 0; ni < 4; ++ni) {
          const int col = bn0 + wc * 64 + ni * 16 + lrow;
          ((float*)outp)[(size_t)row * 1024 + col] = acc[mi][ni][r];
        }
      }
    return;
  }

  const int h0 = bn0 >> 6;             // first of 2 heads in this tile
  const int bb = bm0 >> 11, s0 = bm0 & 2047;
  unsigned short* dst = (unsigned short*)outp;
  __syncthreads();  // all waves done reading As/Bs
  if (MODE == 0) {
    // RoPE in registers (pair partner in lane^1), then Cs[s_local][c_local]
#pragma unroll
    for (int mi = 0; mi < 4; ++mi)
#pragma unroll
      for (int ni = 0; ni < 4; ++ni) {
        const int col = wc * 64 + ni * 16 + lrow;
        const int d = col & 63;
        const float invf = exp2f((float)(d & ~1) * (-13.287712379549609f / 64.0f));
#pragma unroll
        for (int r = 0; r < 4; ++r) {
          const int row = wr * 64 + mi * 16 + hi * 4 + r;
          const float p = (float)pos[bm0 + row];
          float sn, cs;
          sincosf(p * invf, &sn, &cs);
          const float v = acc[mi][ni][r];
          const float other = __shfl_xor(v, 1);
          const float rv = (d & 1) ? (other * sn + v * cs) : (v * cs - other * sn);
          smem[row * 136 + col] = f2bf(rv);
        }
      }
    __syncthreads();
#pragma unroll
    for (int it = 0; it < 8; ++it) {
      const int idx = wave * 8 + it;
      const int hl = idx >> 4, sg = idx & 15;
      const int sl = sg * 8 + (lane >> 3);
      const int ch = (lane & 7) * 8;
      const bf16x8 val = *(const bf16x8*)&smem[sl * 136 + hl * 64 + ch];
      *(bf16x8*)&dst[((size_t)(bb * 16 + h0 + hl) * 2048 + s0 + sl) * 64 + ch] = val;
    }
  } else {
    // V: CsT[c_local][s_local] (transpose at LDS-write, packed r quad = b64)
#pragma unroll
    for (int mi = 0; mi < 4; ++mi)
#pragma unroll
      for (int ni = 0; ni < 4; ++ni) {
        const int col = wc * 64 + ni * 16 + lrow;
        ushort4 pk;
        pk.x = f2bf(acc[mi][ni][0]); pk.y = f2bf(acc[mi][ni][1]);
        pk.z = f2bf(acc[mi][ni][2]); pk.w = f2bf(acc[mi][ni][3]);
        *(ushort4*)&smem[col * 136 + wr * 64 + mi * 16 + hi * 4] = pk;
      }
    __syncthreads();
#pragma unroll
    for (int it = 0; it < 8; ++it) {
      const int idx = wave * 8 + it;
      const int cl = idx * 4 + (lane >> 4);
      const int sc = (lane & 15) * 8;
      const bf16x8 val = *(const bf16x8*)&smem[cl * 136 + sc];
      *(bf16x8*)&dst[((size_t)(bb * 16 + h0 + (cl >> 6)) * 64 + (cl & 63)) * 2048 + s0 + sc] = val;
    }
  }
}

// ---------------- causal flash attention (swapped QK^T, LDS-staged K/V) ----------------
__global__ __launch_bounds__(256) void attn_fwd(const unsigned short* __restrict__ Q,
                                                const unsigned short* __restrict__ Kk,
                                                const unsigned short* __restrict__ Vt,
                                                unsigned short* __restrict__ O) {
  __shared__ __align__(16) unsigned short Ks[4096];   // [64][64] swizzled
  __shared__ __align__(16) unsigned short Vs[4096];   // [64 d][64 kv] swizzled
  __shared__ __align__(16) unsigned short Plds[4][16][72];
  const int p = blockIdx.x;
  const int L = (p & 7) * 128 + (p >> 3);  // XCD swizzle: 8 heads/XCD
  const int bh = L >> 4, pair = L & 15;
  const int tid = threadIdx.x;
  const int lane = tid & 63, wave = tid >> 6;
  const int lrow = lane & 15, hi = lane >> 4;
  const unsigned short* Qb = Q + (size_t)bh * 2048 * 64;
  const unsigned short* Kb = Kk + (size_t)bh * 2048 * 64;
  const unsigned short* Vb = Vt + (size_t)bh * 64 * 2048;
  const int rowA = tid >> 3;
  const int colA = ((tid & 7) ^ (rowA & 7)) * 8;
  const int rowB = rowA + 32;
  const int colB = ((tid & 7) ^ (rowB & 7)) * 8;
  char* kBase0 = (char*)Ks + wave * 1024;
  char* kBase1 = (char*)Ks + 4096 + wave * 1024;
  char* vBase0 = (char*)Vs + wave * 1024;
  char* vBase1 = (char*)Vs + 4096 + wave * 1024;
  const int b = bh >> 4, h = bh & 15;
  const f32x4 z = {0.f, 0.f, 0.f, 0.f};
  constexpr float SCALE = 0.18033688011112042f;  // 0.125 * log2(e)

  for (int half = 0; half < 2; ++half) {
    const int qb = half ? (31 - pair) : pair;
    const int qrow = qb * 64 + wave * 16;
    const int qg = qrow + lrow;
    const bf16x8 qf0 = *(const bf16x8*)(Qb + (size_t)qg * 64 + hi * 8);
    const bf16x8 qf1 = *(const bf16x8*)(Qb + (size_t)qg * 64 + 32 + hi * 8);
    f32x4 acc[4] = {z, z, z, z};
    float m = -1e30f, l = 0.f;

    for (int t = 0; t <= qb; ++t) {
      const int kv0 = t * 64;
      __syncthreads();
      gload16(Kb + (size_t)(kv0 + rowA) * 64 + colA, kBase0);
      gload16(Kb + (size_t)(kv0 + rowB) * 64 + colB, kBase1);
      gload16(Vb + (size_t)rowA * 2048 + kv0 + colA, vBase0);
      gload16(Vb + (size_t)rowB * 2048 + kv0 + colB, vBase1);
      __syncthreads();

      f32x4 st[4];
#pragma unroll
      for (int n = 0; n < 4; ++n) {
        const int rk = n * 16 + lrow;
        const int sw = lrow & 7;
        const bf16x8 kf0 = *(const bf16x8*)((char*)Ks + rk * 128 + ((hi ^ sw) * 16));
        const bf16x8 kf1 = *(const bf16x8*)((char*)Ks + rk * 128 + (((4 + hi) ^ sw) * 16));
        st[n] = MFMA_BF16(kf0, qf0, z);
        st[n] = MFMA_BF16(kf1, qf1, st[n]);
      }
      float pv[16];
      float pmax = -1e30f;
      const bool diag = (t == qb);
#pragma unroll
      for (int n = 0; n < 4; ++n)
#pragma unroll
        for (int r = 0; r < 4; ++r) {
          float v = st[n][r] * SCALE;
          if (diag && (kv0 + n * 16 + hi * 4 + r > qg)) v = -1e30f;
          pv[n * 4 + r] = v;
          pmax = fmaxf(pmax, v);
        }
      pmax = fmaxf(pmax, __shfl_xor(pmax, 16));
      pmax = fmaxf(pmax, __shfl_xor(pmax, 32));
      const float newm = fmaxf(m, pmax);
      const float scl = exp2f(m - newm);
      float rs = 0.f;
#pragma unroll
      for (int i = 0; i < 16; ++i) {
        pv[i] = exp2f(pv[i] - newm);
        rs += pv[i];
      }
      rs += __shfl_xor(rs, 16);
      rs += __shfl_xor(rs, 32);
      l = l * scl + rs;
      m = newm;
#pragma unroll
      for (int dt = 0; dt < 4; ++dt) acc[dt] *= scl;
#pragma unroll
      for (int n = 0; n < 4; ++n) {
        ushort4 pk;
        pk.x = f2bf(pv[n * 4 + 0]); pk.y = f2bf(pv[n * 4 + 1]);
        pk.z = f2bf(pv[n * 4 + 2]); pk.w = f2bf(pv[n * 4 + 3]);
        *(ushort4*)&Plds[wave][lrow][n * 16 + hi * 4] = pk;
      }
      const bf16x8 pf0 = *(const bf16x8*)&Plds[wave][lrow][hi * 8];
      const bf16x8 pf1 = *(const bf16x8*)&Plds[wave][lrow][32 + hi * 8];
#pragma unroll
      for (int dt = 0; dt < 4; ++dt) {
        const int rv = dt * 16 + lrow;
        const int sw = lrow & 7;
        const bf16x8 vf0 = *(const bf16x8*)((char*)Vs + rv * 128 + ((hi ^ sw) * 16));
        const bf16x8 vf1 = *(const bf16x8*)((char*)Vs + rv * 128 + (((4 + hi) ^ sw) * 16));
        acc[dt] = MFMA_BF16(vf0, pf0, acc[dt]);
        acc[dt] = MFMA_BF16(vf1, pf1, acc[dt]);
      }
    }

    const float inv = 1.0f / l;
#pragma unroll
    for (int dt = 0; dt < 4; ++dt) {
      ushort4 ov;
      ov.x = f2bf(acc[dt][0] * inv); ov.y = f2bf(acc[dt][1] * inv);
      ov.z = f2bf(acc[dt][2] * inv); ov.w = f2bf(acc[dt][3] * inv);
      *(ushort4*)&O[((size_t)b * 2048 + qg) * 1024 + h * 64 + dt * 16 + hi * 4] = ov;
    }
  }
}

extern "C" void kernel_launch(void* const* d_in, const int* in_sizes, int n_in,
                              void* d_out, int out_size, void* d_ws, size_t ws_size,
                              hipStream_t stream) {
  const float* x  = (const float*)d_in[0];
  const float* qw = (const float*)d_in[1];
  const float* kw = (const float*)d_in[2];
  const float* vw = (const float*)d_in[3];
  const float* ow = (const float*)d_in[4];
  const int* pos  = (const int*)d_in[5];
  float* out = (float*)d_out;

  unsigned short* xb  = (unsigned short*)d_ws;            // [8192,1024]
  unsigned short* qwb = xb  + (size_t)8192 * 1024;        // [1024,1024] x4
  unsigned short* kwb = qwb + (size_t)1024 * 1024;
  unsigned short* vwb = kwb + (size_t)1024 * 1024;
  unsigned short* owb = vwb + (size_t)1024 * 1024;
  unsigned short* Qr  = owb + (size_t)1024 * 1024;        // [BH,S,DK]
  unsigned short* Kr  = Qr  + (size_t)8192 * 1024;        // [BH,S,DK]
  unsigned short* Vtr = Kr  + (size_t)8192 * 1024;        // [BH,DK,S]
  unsigned short* AO  = Vtr + (size_t)8192 * 1024;        // [8192,1024]

  cvt_f32_bf16<<<8192, 256, 0, stream>>>(x,  xb,  8192 * 1024);
  cvt_f32_bf16<<<1024, 256, 0, stream>>>(qw, qwb, 1024 * 1024);
  cvt_f32_bf16<<<1024, 256, 0, stream>>>(kw, kwb, 1024 * 1024);
  cvt_f32_bf16<<<1024, 256, 0, stream>>>(vw, vwb, 1024 * 1024);
  cvt_f32_bf16<<<1024, 256, 0, stream>>>(ow, owb, 1024 * 1024);

  dim3 gg(8, 64);  // (1024/128, 8192/128)
  gemm_bt<0><<<gg, 256, 0, stream>>>(xb, qwb, Qr,  pos);
  gemm_bt<0><<<gg, 256, 0, stream>>>(xb, kwb, Kr,  pos);
  gemm_bt<1><<<gg, 256, 0, stream>>>(xb, vwb, Vtr, pos);
  attn_fwd<<<1024, 256, 0, stream>>>(Qr, Kr, Vtr, AO);
  gemm_bt<2><<<gg, 256, 0, stream>>>(AO, owb, out, nullptr);
}

// Round 6
// 261.698 us; speedup vs baseline: 2.6759x; 2.1280x over previous
//
#include <hip/hip_runtime.h>
#include <hip/hip_bf16.h>

using bf16x8 = __attribute__((ext_vector_type(8))) short;
using f32x4  = __attribute__((ext_vector_type(4))) float;

#define MFMA_BF16(a, b, c) __builtin_amdgcn_mfma_f32_16x16x32_bf16((a), (b), (c), 0, 0, 0)

__device__ __forceinline__ unsigned short f2bf(float x) {
  union { float f; unsigned int u; } v; v.f = x;
  unsigned int r = v.u + 0x7fffu + ((v.u >> 16) & 1u);
  return (unsigned short)(r >> 16);
}

__device__ __forceinline__ void gload16(const void* g, void* l) {
  __builtin_amdgcn_global_load_lds(
      (const __attribute__((address_space(1))) unsigned int*)g,
      (__attribute__((address_space(3))) unsigned int*)l, 16, 0, 0);
}

// ---------------- f32 -> bf16 convert (all 5 inputs, one launch) ----------------
// dst layout: xb[8192*1024] | qwb | kwb | vwb | owb (each 1024*1024), contiguous.
__global__ __launch_bounds__(256) void cvt_all(const float* __restrict__ x,
                                               const float* __restrict__ qw,
                                               const float* __restrict__ kw,
                                               const float* __restrict__ vw,
                                               const float* __restrict__ ow,
                                               unsigned short* __restrict__ out) {
  const int bid = blockIdx.x;
  int seg, loc;
  if (bid < 8192) { seg = 0; loc = bid; }
  else { seg = 1 + ((bid - 8192) >> 10); loc = (bid - 8192) & 1023; }
  const float* srcs[5] = {x, qw, kw, vw, ow};
  const float* in = srcs[seg];
  const size_t obase = (seg == 0) ? 0 : ((size_t)8192 + (size_t)(seg - 1) * 1024) * 1024;
  const int i = loc * 1024 + threadIdx.x * 4;
  float4 f = *(const float4*)(in + i);
  ushort4 o;
  o.x = f2bf(f.x); o.y = f2bf(f.y); o.z = f2bf(f.z); o.w = f2bf(f.w);
  *(ushort4*)(out + obase + i) = o;
}

// ---------------- BT-GEMM: C[m][n] = sum_k A[m][k] * Bw[n][k] ----------------
// M=8192, N=K=1024 baked. 64x128 block tile (grid 8x128 = 1024 blocks = 4/CU),
// BK=32, 4 waves as 2x2, each wave 32x64 (acc[2][4]). global_load_lds width-16
// staging, linear LDS. Epilogues route through LDS so global stores are 16 B
// contiguous per lane.
// MODE 0: RoPE epilogue, bf16 out [BH,S,DK] (Q or K)
// MODE 1: bf16 out transposed [BH,DK,S]     (V)
// MODE 2: f32 out [M,1024]                  (final projection)
template <int MODE>
__global__ __launch_bounds__(256) void gemm_bt(const unsigned short* __restrict__ A,
                                               const unsigned short* __restrict__ Bw,
                                               void* __restrict__ outp,
                                               const int* __restrict__ pos) {
  constexpr int K = 1024;
  constexpr int SMEM_ELEMS = (MODE == 0) ? 64 * 136 : (MODE == 1 ? 128 * 72 : 6144);
  __shared__ __align__(16) unsigned short smem[SMEM_ELEMS];  // staging 12KB; MODE<2 reused as C-tile
  const int tid  = threadIdx.x;
  const int lane = tid & 63, wave = tid >> 6;
  const int wr = wave >> 1, wc = wave & 1;   // wave tile: rows [wr*32,+32), cols [wc*64,+64)
  const int bm0 = blockIdx.y * 64, bn0 = blockIdx.x * 128;
  const int lrow = lane & 15, hi = lane >> 4, lko = hi * 8;
  const int srow = tid >> 2, scol = (tid & 3) * 8;   // staging: 4 chunks/row
  const unsigned short* gA = A + (size_t)(bm0 + srow) * K + scol;   // srow<64
  const unsigned short* gB = Bw + (size_t)(bn0 + srow) * K + scol;  // +64*K second round
  char* lA = (char*)smem + wave * 1024;            // A staging bytes [0,4096)
  char* lB = (char*)smem + 4096 + wave * 1024;     // B staging bytes [4096,12288)
  const f32x4 z = {0.f, 0.f, 0.f, 0.f};
  f32x4 acc[2][4];
#pragma unroll
  for (int i = 0; i < 2; ++i)
#pragma unroll
    for (int j = 0; j < 4; ++j) acc[i][j] = z;

  for (int k0 = 0; k0 < K; k0 += 32) {
    __syncthreads();
    gload16(gA + k0, lA);
    gload16(gB + k0, lB);
    gload16(gB + k0 + (size_t)64 * K, lB + 4096);
    __syncthreads();
    bf16x8 af[2], bfr[4];
#pragma unroll
    for (int mi = 0; mi < 2; ++mi)
      af[mi] = *(const bf16x8*)&smem[(wr * 32 + mi * 16 + lrow) * 32 + lko];
#pragma unroll
    for (int ni = 0; ni < 4; ++ni)
      bfr[ni] = *(const bf16x8*)&smem[2048 + (wc * 64 + ni * 16 + lrow) * 32 + lko];
#pragma unroll
    for (int mi = 0; mi < 2; ++mi)
#pragma unroll
      for (int ni = 0; ni < 4; ++ni)
        acc[mi][ni] = MFMA_BF16(af[mi], bfr[ni], acc[mi][ni]);
  }

  if (MODE == 2) {
#pragma unroll
    for (int mi = 0; mi < 2; ++mi)
#pragma unroll
      for (int r = 0; r < 4; ++r) {
        const int row = bm0 + wr * 32 + mi * 16 + hi * 4 + r;
#pragma unroll
        for (int ni = 0; ni < 4; ++ni) {
          const int col = bn0 + wc * 64 + ni * 16 + lrow;
          ((float*)outp)[(size_t)row * 1024 + col] = acc[mi][ni][r];
        }
      }
    return;
  }

  const int h0 = bn0 >> 6;             // first of 2 heads in this 128-col tile
  const int bb = bm0 >> 11, s0 = bm0 & 2047;
  unsigned short* dst = (unsigned short*)outp;
  __syncthreads();  // all waves done reading staging
  if (MODE == 0) {
    // RoPE in registers (pair partner in lane^1), C-tile [64 s][136 pad]
#pragma unroll
    for (int mi = 0; mi < 2; ++mi)
#pragma unroll
      for (int ni = 0; ni < 4; ++ni) {
        const int col = wc * 64 + ni * 16 + lrow;
        const int d = col & 63;
        const float invf = exp2f((float)(d & ~1) * (-13.287712379549609f / 64.0f));
#pragma unroll
        for (int r = 0; r < 4; ++r) {
          const int row = wr * 32 + mi * 16 + hi * 4 + r;
          const float p = (float)pos[bm0 + row];
          float sn, cs;
          sincosf(p * invf, &sn, &cs);
          const float v = acc[mi][ni][r];
          const float other = __shfl_xor(v, 1);
          const float rv = (d & 1) ? (other * sn + v * cs) : (v * cs - other * sn);
          smem[row * 136 + col] = f2bf(rv);
        }
      }
    __syncthreads();
    // writeout: 2 heads x 64 rows x 8 chunks(16B) = 1024 chunks, 4 rounds
#pragma unroll
    for (int it = 0; it < 4; ++it) {
      const int c = it * 256 + tid;
      const int hl = c >> 9, rem = c & 511;
      const int sl = rem >> 3, ch = (rem & 7) * 8;
      const bf16x8 val = *(const bf16x8*)&smem[sl * 136 + hl * 64 + ch];
      *(bf16x8*)&dst[((size_t)(bb * 16 + h0 + hl) * 2048 + s0 + sl) * 64 + ch] = val;
    }
  } else {
    // V: C^T tile [128 c][72 pad s] (transpose at LDS-write, packed r-quad = b64)
#pragma unroll
    for (int mi = 0; mi < 2; ++mi)
#pragma unroll
      for (int ni = 0; ni < 4; ++ni) {
        const int col = wc * 64 + ni * 16 + lrow;
        ushort4 pk;
        pk.x = f2bf(acc[mi][ni][0]); pk.y = f2bf(acc[mi][ni][1]);
        pk.z = f2bf(acc[mi][ni][2]); pk.w = f2bf(acc[mi][ni][3]);
        *(ushort4*)&smem[col * 72 + wr * 32 + mi * 16 + hi * 4] = pk;
      }
    __syncthreads();
    // writeout: 128 cols x 8 chunks(16B of s) = 1024 chunks, 4 rounds
#pragma unroll
    for (int it = 0; it < 4; ++it) {
      const int c = it * 256 + tid;
      const int cl = c >> 3, sc = (c & 7) * 8;
      const bf16x8 val = *(const bf16x8*)&smem[cl * 72 + sc];
      *(bf16x8*)&dst[((size_t)(bb * 16 + h0 + (cl >> 6)) * 64 + (cl & 63)) * 2048 + s0 + sc] = val;
    }
  }
}

// ---------------- causal flash attention (swapped QK^T, LDS-staged K/V) ----------------
__global__ __launch_bounds__(256) void attn_fwd(const unsigned short* __restrict__ Q,
                                                const unsigned short* __restrict__ Kk,
                                                const unsigned short* __restrict__ Vt,
                                                unsigned short* __restrict__ O) {
  __shared__ __align__(16) unsigned short Ks[4096];   // [64][64] swizzled
  __shared__ __align__(16) unsigned short Vs[4096];   // [64 d][64 kv] swizzled
  __shared__ __align__(16) unsigned short Plds[4][16][72];
  const int p = blockIdx.x;
  const int L = (p & 7) * 128 + (p >> 3);  // XCD swizzle: 8 heads/XCD
  const int bh = L >> 4, pair = L & 15;
  const int tid = threadIdx.x;
  const int lane = tid & 63, wave = tid >> 6;
  const int lrow = lane & 15, hi = lane >> 4;
  const unsigned short* Qb = Q + (size_t)bh * 2048 * 64;
  const unsigned short* Kb = Kk + (size_t)bh * 2048 * 64;
  const unsigned short* Vb = Vt + (size_t)bh * 64 * 2048;
  const int rowA = tid >> 3;
  const int colA = ((tid & 7) ^ (rowA & 7)) * 8;
  const int rowB = rowA + 32;
  const int colB = ((tid & 7) ^ (rowB & 7)) * 8;
  char* kBase0 = (char*)Ks + wave * 1024;
  char* kBase1 = (char*)Ks + 4096 + wave * 1024;
  char* vBase0 = (char*)Vs + wave * 1024;
  char* vBase1 = (char*)Vs + 4096 + wave * 1024;
  const int b = bh >> 4, h = bh & 15;
  const f32x4 z = {0.f, 0.f, 0.f, 0.f};
  constexpr float SCALE = 0.18033688011112042f;  // 0.125 * log2(e)

  for (int half = 0; half < 2; ++half) {
    const int qb = half ? (31 - pair) : pair;
    const int qrow = qb * 64 + wave * 16;
    const int qg = qrow + lrow;
    const bf16x8 qf0 = *(const bf16x8*)(Qb + (size_t)qg * 64 + hi * 8);
    const bf16x8 qf1 = *(const bf16x8*)(Qb + (size_t)qg * 64 + 32 + hi * 8);
    f32x4 acc[4] = {z, z, z, z};
    float m = -1e30f, l = 0.f;

    for (int t = 0; t <= qb; ++t) {
      const int kv0 = t * 64;
      __syncthreads();
      gload16(Kb + (size_t)(kv0 + rowA) * 64 + colA, kBase0);
      gload16(Kb + (size_t)(kv0 + rowB) * 64 + colB, kBase1);
      gload16(Vb + (size_t)rowA * 2048 + kv0 + colA, vBase0);
      gload16(Vb + (size_t)rowB * 2048 + kv0 + colB, vBase1);
      __syncthreads();

      f32x4 st[4];
#pragma unroll
      for (int n = 0; n < 4; ++n) {
        const int rk = n * 16 + lrow;
        const int sw = lrow & 7;
        const bf16x8 kf0 = *(const bf16x8*)((char*)Ks + rk * 128 + ((hi ^ sw) * 16));
        const bf16x8 kf1 = *(const bf16x8*)((char*)Ks + rk * 128 + (((4 + hi) ^ sw) * 16));
        st[n] = MFMA_BF16(kf0, qf0, z);
        st[n] = MFMA_BF16(kf1, qf1, st[n]);
      }
      float pv[16];
      float pmax = -1e30f;
      const bool diag = (t == qb);
#pragma unroll
      for (int n = 0; n < 4; ++n)
#pragma unroll
        for (int r = 0; r < 4; ++r) {
          float v = st[n][r] * SCALE;
          if (diag && (kv0 + n * 16 + hi * 4 + r > qg)) v = -1e30f;
          pv[n * 4 + r] = v;
          pmax = fmaxf(pmax, v);
        }
      pmax = fmaxf(pmax, __shfl_xor(pmax, 16));
      pmax = fmaxf(pmax, __shfl_xor(pmax, 32));
      const float newm = fmaxf(m, pmax);
      const float scl = exp2f(m - newm);
      float rs = 0.f;
#pragma unroll
      for (int i = 0; i < 16; ++i) {
        pv[i] = exp2f(pv[i] - newm);
        rs += pv[i];
      }
      rs += __shfl_xor(rs, 16);
      rs += __shfl_xor(rs, 32);
      l = l * scl + rs;
      m = newm;
#pragma unroll
      for (int dt = 0; dt < 4; ++dt) acc[dt] *= scl;
#pragma unroll
      for (int n = 0; n < 4; ++n) {
        ushort4 pk;
        pk.x = f2bf(pv[n * 4 + 0]); pk.y = f2bf(pv[n * 4 + 1]);
        pk.z = f2bf(pv[n * 4 + 2]); pk.w = f2bf(pv[n * 4 + 3]);
        *(ushort4*)&Plds[wave][lrow][n * 16 + hi * 4] = pk;
      }
      const bf16x8 pf0 = *(const bf16x8*)&Plds[wave][lrow][hi * 8];
      const bf16x8 pf1 = *(const bf16x8*)&Plds[wave][lrow][32 + hi * 8];
#pragma unroll
      for (int dt = 0; dt < 4; ++dt) {
        const int rv = dt * 16 + lrow;
        const int sw = lrow & 7;
        const bf16x8 vf0 = *(const bf16x8*)((char*)Vs + rv * 128 + ((hi ^ sw) * 16));
        const bf16x8 vf1 = *(const bf16x8*)((char*)Vs + rv * 128 + (((4 + hi) ^ sw) * 16));
        acc[dt] = MFMA_BF16(vf0, pf0, acc[dt]);
        acc[dt] = MFMA_BF16(vf1, pf1, acc[dt]);
      }
    }

    const float inv = 1.0f / l;
#pragma unroll
    for (int dt = 0; dt < 4; ++dt) {
      ushort4 ov;
      ov.x = f2bf(acc[dt][0] * inv); ov.y = f2bf(acc[dt][1] * inv);
      ov.z = f2bf(acc[dt][2] * inv); ov.w = f2bf(acc[dt][3] * inv);
      *(ushort4*)&O[((size_t)b * 2048 + qg) * 1024 + h * 64 + dt * 16 + hi * 4] = ov;
    }
  }
}

extern "C" void kernel_launch(void* const* d_in, const int* in_sizes, int n_in,
                              void* d_out, int out_size, void* d_ws, size_t ws_size,
                              hipStream_t stream) {
  const float* x  = (const float*)d_in[0];
  const float* qw = (const float*)d_in[1];
  const float* kw = (const float*)d_in[2];
  const float* vw = (const float*)d_in[3];
  const float* ow = (const float*)d_in[4];
  const int* pos  = (const int*)d_in[5];
  float* out = (float*)d_out;

  unsigned short* xb  = (unsigned short*)d_ws;            // [8192,1024]
  unsigned short* qwb = xb  + (size_t)8192 * 1024;        // [1024,1024] x4
  unsigned short* kwb = qwb + (size_t)1024 * 1024;
  unsigned short* vwb = kwb + (size_t)1024 * 1024;
  unsigned short* owb = vwb + (size_t)1024 * 1024;
  unsigned short* Qr  = owb + (size_t)1024 * 1024;        // [BH,S,DK]
  unsigned short* Kr  = Qr  + (size_t)8192 * 1024;        // [BH,S,DK]
  unsigned short* Vtr = Kr  + (size_t)8192 * 1024;        // [BH,DK,S]
  unsigned short* AO  = Vtr + (size_t)8192 * 1024;        // [8192,1024]

  cvt_all<<<12288, 256, 0, stream>>>(x, qw, kw, vw, ow, xb);

  dim3 gg(8, 128);  // (1024/128, 8192/64)
  gemm_bt<0><<<gg, 256, 0, stream>>>(xb, qwb, Qr,  pos);
  gemm_bt<0><<<gg, 256, 0, stream>>>(xb, kwb, Kr,  pos);
  gemm_bt<1><<<gg, 256, 0, stream>>>(xb, vwb, Vtr, pos);
  attn_fwd<<<1024, 256, 0, stream>>>(Qr, Kr, Vtr, AO);
  gemm_bt<2><<<gg, 256, 0, stream>>>(AO, owb, out, nullptr);
}

// Round 7
// 231.942 us; speedup vs baseline: 3.0192x; 1.1283x over previous
//
#include <hip/hip_runtime.h>
#include <hip/hip_bf16.h>

using bf16x8 = __attribute__((ext_vector_type(8))) short;
using f32x4  = __attribute__((ext_vector_type(4))) float;

#define MFMA_BF16(a, b, c) __builtin_amdgcn_mfma_f32_16x16x32_bf16((a), (b), (c), 0, 0, 0)

__device__ __forceinline__ unsigned short f2bf(float x) {
  union { float f; unsigned int u; } v; v.f = x;
  unsigned int r = v.u + 0x7fffu + ((v.u >> 16) & 1u);
  return (unsigned short)(r >> 16);
}

__device__ __forceinline__ unsigned int cvtpk(float a, float b) {
  __hip_bfloat162 h = __float22bfloat162_rn(make_float2(a, b));
  unsigned int u; __builtin_memcpy(&u, &h, 4); return u;
}

__device__ __forceinline__ void gload16(const void* g, void* l) {
  __builtin_amdgcn_global_load_lds(
      (const __attribute__((address_space(1))) unsigned int*)g,
      (__attribute__((address_space(3))) unsigned int*)l, 16, 0, 0);
}

// ---------------- f32 -> bf16 convert (all 5 inputs, one launch) ----------------
__global__ __launch_bounds__(256) void cvt_all(const float* __restrict__ x,
                                               const float* __restrict__ qw,
                                               const float* __restrict__ kw,
                                               const float* __restrict__ vw,
                                               const float* __restrict__ ow,
                                               unsigned short* __restrict__ out) {
  const int bid = blockIdx.x;
  int seg, loc;
  if (bid < 8192) { seg = 0; loc = bid; }
  else { seg = 1 + ((bid - 8192) >> 10); loc = (bid - 8192) & 1023; }
  const float* srcs[5] = {x, qw, kw, vw, ow};
  const float* in = srcs[seg];
  const size_t obase = (seg == 0) ? 0 : ((size_t)8192 + (size_t)(seg - 1) * 1024) * 1024;
  const int i = loc * 1024 + threadIdx.x * 4;
  float4 f = *(const float4*)(in + i);
  ushort4 o;
  o.x = f2bf(f.x); o.y = f2bf(f.y); o.z = f2bf(f.z); o.w = f2bf(f.w);
  *(ushort4*)(out + obase + i) = o;
}

// ---------------- BT-GEMM: C[m][n] = sum_k A[m][k] * Bw[n][k] ----------------
// M=8192, N=K=1024 baked. 64x128 block tile (grid 8x128 = 1024 blocks = 4/CU),
// BK=32, 4 waves as 2x2, each wave 32x64 (acc[2][4]).
// MODE 0: RoPE epilogue, bf16 out [BH,S,DK] (Q or K)
// MODE 1: bf16 out transposed [BH,DK,S]     (V)
// MODE 2: f32 out [M,1024]                  (final projection)
template <int MODE>
__global__ __launch_bounds__(256) void gemm_bt(const unsigned short* __restrict__ A,
                                               const unsigned short* __restrict__ Bw,
                                               void* __restrict__ outp,
                                               const int* __restrict__ pos) {
  constexpr int K = 1024;
  constexpr int SMEM_ELEMS = (MODE == 0) ? 64 * 136 : (MODE == 1 ? 128 * 72 : 6144);
  __shared__ __align__(16) unsigned short smem[SMEM_ELEMS];
  const int tid  = threadIdx.x;
  const int lane = tid & 63, wave = tid >> 6;
  const int wr = wave >> 1, wc = wave & 1;
  const int bm0 = blockIdx.y * 64, bn0 = blockIdx.x * 128;
  const int lrow = lane & 15, hi = lane >> 4, lko = hi * 8;
  const int srow = tid >> 2, scol = (tid & 3) * 8;
  const unsigned short* gA = A + (size_t)(bm0 + srow) * K + scol;
  const unsigned short* gB = Bw + (size_t)(bn0 + srow) * K + scol;
  char* lA = (char*)smem + wave * 1024;
  char* lB = (char*)smem + 4096 + wave * 1024;
  const f32x4 z = {0.f, 0.f, 0.f, 0.f};
  f32x4 acc[2][4];
#pragma unroll
  for (int i = 0; i < 2; ++i)
#pragma unroll
    for (int j = 0; j < 4; ++j) acc[i][j] = z;

  for (int k0 = 0; k0 < K; k0 += 32) {
    __syncthreads();
    gload16(gA + k0, lA);
    gload16(gB + k0, lB);
    gload16(gB + k0 + (size_t)64 * K, lB + 4096);
    __syncthreads();
    bf16x8 af[2], bfr[4];
#pragma unroll
    for (int mi = 0; mi < 2; ++mi)
      af[mi] = *(const bf16x8*)&smem[(wr * 32 + mi * 16 + lrow) * 32 + lko];
#pragma unroll
    for (int ni = 0; ni < 4; ++ni)
      bfr[ni] = *(const bf16x8*)&smem[2048 + (wc * 64 + ni * 16 + lrow) * 32 + lko];
#pragma unroll
    for (int mi = 0; mi < 2; ++mi)
#pragma unroll
      for (int ni = 0; ni < 4; ++ni)
        acc[mi][ni] = MFMA_BF16(af[mi], bfr[ni], acc[mi][ni]);
  }

  if (MODE == 2) {
#pragma unroll
    for (int mi = 0; mi < 2; ++mi)
#pragma unroll
      for (int r = 0; r < 4; ++r) {
        const int row = bm0 + wr * 32 + mi * 16 + hi * 4 + r;
#pragma unroll
        for (int ni = 0; ni < 4; ++ni) {
          const int col = bn0 + wc * 64 + ni * 16 + lrow;
          ((float*)outp)[(size_t)row * 1024 + col] = acc[mi][ni][r];
        }
      }
    return;
  }

  const int h0 = bn0 >> 6;
  const int bb = bm0 >> 11, s0 = bm0 & 2047;
  unsigned short* dst = (unsigned short*)outp;
  __syncthreads();
  if (MODE == 0) {
#pragma unroll
    for (int mi = 0; mi < 2; ++mi)
#pragma unroll
      for (int ni = 0; ni < 4; ++ni) {
        const int col = wc * 64 + ni * 16 + lrow;
        const int d = col & 63;
        const float invf = exp2f((float)(d & ~1) * (-13.287712379549609f / 64.0f));
#pragma unroll
        for (int r = 0; r < 4; ++r) {
          const int row = wr * 32 + mi * 16 + hi * 4 + r;
          const float p = (float)pos[bm0 + row];
          float sn, cs;
          sincosf(p * invf, &sn, &cs);
          const float v = acc[mi][ni][r];
          const float other = __shfl_xor(v, 1);
          const float rv = (d & 1) ? (other * sn + v * cs) : (v * cs - other * sn);
          smem[row * 136 + col] = f2bf(rv);
        }
      }
    __syncthreads();
#pragma unroll
    for (int it = 0; it < 4; ++it) {
      const int c = it * 256 + tid;
      const int hl = c >> 9, rem = c & 511;
      const int sl = rem >> 3, ch = (rem & 7) * 8;
      const bf16x8 val = *(const bf16x8*)&smem[sl * 136 + hl * 64 + ch];
      *(bf16x8*)&dst[((size_t)(bb * 16 + h0 + hl) * 2048 + s0 + sl) * 64 + ch] = val;
    }
  } else {
#pragma unroll
    for (int mi = 0; mi < 2; ++mi)
#pragma unroll
      for (int ni = 0; ni < 4; ++ni) {
        const int col = wc * 64 + ni * 16 + lrow;
        ushort4 pk;
        pk.x = f2bf(acc[mi][ni][0]); pk.y = f2bf(acc[mi][ni][1]);
        pk.z = f2bf(acc[mi][ni][2]); pk.w = f2bf(acc[mi][ni][3]);
        *(ushort4*)&smem[col * 72 + wr * 32 + mi * 16 + hi * 4] = pk;
      }
    __syncthreads();
#pragma unroll
    for (int it = 0; it < 4; ++it) {
      const int c = it * 256 + tid;
      const int cl = c >> 3, sc = (c & 7) * 8;
      const bf16x8 val = *(const bf16x8*)&smem[cl * 72 + sc];
      *(bf16x8*)&dst[((size_t)(bb * 16 + h0 + (cl >> 6)) * 64 + (cl & 63)) * 2048 + s0 + sc] = val;
    }
  }
}

// ---------------- causal flash attention (swapped QK^T, LDS-staged K/V) ----------------
// VALU-lean softmax: diag-hoisted masking, fma-folded scale, defer-max (THR=8,
// log2 domain), cvt_pk bf16 packing, XOR-swizzled Plds (conflict-free roundtrip).
__global__ __launch_bounds__(256) void attn_fwd(const unsigned short* __restrict__ Q,
                                                const unsigned short* __restrict__ Kk,
                                                const unsigned short* __restrict__ Vt,
                                                unsigned short* __restrict__ O) {
  __shared__ __align__(16) unsigned short Ks[4096];     // [64][64] swizzled
  __shared__ __align__(16) unsigned short Vs[4096];     // [64 d][64 kv] swizzled
  __shared__ __align__(16) unsigned short Plds[4][16][64];  // chunk-XOR swizzled
  const int p = blockIdx.x;
  const int L = (p & 7) * 128 + (p >> 3);  // XCD swizzle: 8 heads/XCD
  const int bh = L >> 4, pair = L & 15;
  const int tid = threadIdx.x;
  const int lane = tid & 63, wave = tid >> 6;
  const int lrow = lane & 15, hi = lane >> 4;
  const int l7 = lrow & 7;
  const unsigned short* Qb = Q + (size_t)bh * 2048 * 64;
  const unsigned short* Kb = Kk + (size_t)bh * 2048 * 64;
  const unsigned short* Vb = Vt + (size_t)bh * 64 * 2048;
  const int rowA = tid >> 3;
  const int colA = ((tid & 7) ^ (rowA & 7)) * 8;
  const int rowB = rowA + 32;
  const int colB = ((tid & 7) ^ (rowB & 7)) * 8;
  char* kBase0 = (char*)Ks + wave * 1024;
  char* kBase1 = (char*)Ks + 4096 + wave * 1024;
  char* vBase0 = (char*)Vs + wave * 1024;
  char* vBase1 = (char*)Vs + 4096 + wave * 1024;
  const int b = bh >> 4, h = bh & 15;
  const f32x4 z = {0.f, 0.f, 0.f, 0.f};
  constexpr float SCALE = 0.18033688011112042f;  // 0.125 * log2(e)

  for (int half = 0; half < 2; ++half) {
    const int qb = half ? (31 - pair) : pair;
    const int qrow = qb * 64 + wave * 16;
    const int qg = qrow + lrow;
    const bf16x8 qf0 = *(const bf16x8*)(Qb + (size_t)qg * 64 + hi * 8);
    const bf16x8 qf1 = *(const bf16x8*)(Qb + (size_t)qg * 64 + 32 + hi * 8);
    f32x4 acc[4] = {z, z, z, z};
    float m = -1e30f, l = 0.f;

    auto process = [&](int t, bool diag) {
      const int kv0 = t * 64;
      __syncthreads();  // prev tile's LDS reads done
      gload16(Kb + (size_t)(kv0 + rowA) * 64 + colA, kBase0);
      gload16(Kb + (size_t)(kv0 + rowB) * 64 + colB, kBase1);
      gload16(Vb + (size_t)rowA * 2048 + kv0 + colA, vBase0);
      gload16(Vb + (size_t)rowB * 2048 + kv0 + colB, vBase1);
      __syncthreads();  // staged tiles visible

      f32x4 st[4];
#pragma unroll
      for (int n = 0; n < 4; ++n) {
        const int rk = n * 16 + lrow;
        const bf16x8 kf0 = *(const bf16x8*)((char*)Ks + rk * 128 + ((hi ^ l7) * 16));
        const bf16x8 kf1 = *(const bf16x8*)((char*)Ks + rk * 128 + (((4 + hi) ^ l7) * 16));
        st[n] = MFMA_BF16(kf0, qf0, z);
        st[n] = MFMA_BF16(kf1, qf1, st[n]);
      }
      if (diag) {
#pragma unroll
        for (int n = 0; n < 4; ++n)
#pragma unroll
          for (int r = 0; r < 4; ++r)
            if (kv0 + n * 16 + hi * 4 + r > qg) st[n][r] = -3e38f;
      }
      float pmaxr = -3e38f;
#pragma unroll
      for (int n = 0; n < 4; ++n)
#pragma unroll
        for (int r = 0; r < 4; ++r) pmaxr = fmaxf(pmaxr, st[n][r]);
      pmaxr = fmaxf(pmaxr, __shfl_xor(pmaxr, 16));
      pmaxr = fmaxf(pmaxr, __shfl_xor(pmaxr, 32));
      const float pms = pmaxr * SCALE;
      if (!__all(pms <= m + 8.0f)) {       // defer-max: rescale only on real growth
        const float newm = fmaxf(m, pms);
        const float scl = exp2f(m - newm);
        m = newm;
        l *= scl;
#pragma unroll
        for (int dt = 0; dt < 4; ++dt) acc[dt] *= scl;
      }
      float pe[16];
      float rs = 0.f;
#pragma unroll
      for (int n = 0; n < 4; ++n)
#pragma unroll
        for (int r = 0; r < 4; ++r) {
          const float e = exp2f(fmaf(st[n][r], SCALE, -m));
          pe[n * 4 + r] = e;
          rs += e;
        }
      rs += __shfl_xor(rs, 16);
      rs += __shfl_xor(rs, 32);
      l += rs;
      // P -> Plds, chunk-XOR swizzle: elem x of row lrow lives at chunk (x>>3)^l7
#pragma unroll
      for (int n = 0; n < 4; ++n) {
        uint2 pk;
        pk.x = cvtpk(pe[n * 4 + 0], pe[n * 4 + 1]);
        pk.y = cvtpk(pe[n * 4 + 2], pe[n * 4 + 3]);
        const int eo = ((((n * 2 + (hi >> 1)) ^ l7) << 3) | ((hi & 1) << 2));
        *(uint2*)&Plds[wave][lrow][eo] = pk;
      }
      const bf16x8 pf0 = *(const bf16x8*)&Plds[wave][lrow][(hi ^ l7) << 3];
      const bf16x8 pf1 = *(const bf16x8*)&Plds[wave][lrow][((4 + hi) ^ l7) << 3];
#pragma unroll
      for (int dt = 0; dt < 4; ++dt) {
        const int rv = dt * 16 + lrow;
        const bf16x8 vf0 = *(const bf16x8*)((char*)Vs + rv * 128 + ((hi ^ l7) * 16));
        const bf16x8 vf1 = *(const bf16x8*)((char*)Vs + rv * 128 + (((4 + hi) ^ l7) * 16));
        acc[dt] = MFMA_BF16(vf0, pf0, acc[dt]);
        acc[dt] = MFMA_BF16(vf1, pf1, acc[dt]);
      }
    };

#pragma unroll 1
    for (int t = 0; t < qb; ++t) process(t, false);
    process(qb, true);

    const float inv = 1.0f / l;
#pragma unroll
    for (int dt = 0; dt < 4; ++dt) {
      uint2 ov;
      ov.x = cvtpk(acc[dt][0] * inv, acc[dt][1] * inv);
      ov.y = cvtpk(acc[dt][2] * inv, acc[dt][3] * inv);
      *(uint2*)&O[((size_t)b * 2048 + qg) * 1024 + h * 64 + dt * 16 + hi * 4] = ov;
    }
  }
}

extern "C" void kernel_launch(void* const* d_in, const int* in_sizes, int n_in,
                              void* d_out, int out_size, void* d_ws, size_t ws_size,
                              hipStream_t stream) {
  const float* x  = (const float*)d_in[0];
  const float* qw = (const float*)d_in[1];
  const float* kw = (const float*)d_in[2];
  const float* vw = (const float*)d_in[3];
  const float* ow = (const float*)d_in[4];
  const int* pos  = (const int*)d_in[5];
  float* out = (float*)d_out;

  unsigned short* xb  = (unsigned short*)d_ws;            // [8192,1024]
  unsigned short* qwb = xb  + (size_t)8192 * 1024;        // [1024,1024] x4
  unsigned short* kwb = qwb + (size_t)1024 * 1024;
  unsigned short* vwb = kwb + (size_t)1024 * 1024;
  unsigned short* owb = vwb + (size_t)1024 * 1024;
  unsigned short* Qr  = owb + (size_t)1024 * 1024;        // [BH,S,DK]
  unsigned short* Kr  = Qr  + (size_t)8192 * 1024;        // [BH,S,DK]
  unsigned short* Vtr = Kr  + (size_t)8192 * 1024;        // [BH,DK,S]
  unsigned short* AO  = Vtr + (size_t)8192 * 1024;        // [8192,1024]

  cvt_all<<<12288, 256, 0, stream>>>(x, qw, kw, vw, ow, xb);

  dim3 gg(8, 128);  // (1024/128, 8192/64)
  gemm_bt<0><<<gg, 256, 0, stream>>>(xb, qwb, Qr,  pos);
  gemm_bt<0><<<gg, 256, 0, stream>>>(xb, kwb, Kr,  pos);
  gemm_bt<1><<<gg, 256, 0, stream>>>(xb, vwb, Vtr, pos);
  attn_fwd<<<1024, 256, 0, stream>>>(Qr, Kr, Vtr, AO);
  gemm_bt<2><<<gg, 256, 0, stream>>>(AO, owb, out, nullptr);
}